// Round 7
// baseline (436.649 us; speedup 1.0000x reference)
//
#include <hip/hip_runtime.h>
#include <hip/hip_bf16.h>
#include <math.h>

// Problem constants
#define NN   3000
#define EE   96000
#define BB   64
#define CIN  8
#define MID  16
#define G1   32
#define G2   8
#define FC1N 512
#define FC2N 128
#define OUTN 10
#define EPSV 1e-5f

#define BC   (BB * CIN)          // 512
#define HROW (NN * MID)          // 48000 floats per batch row of hb
#define D0   (G2 * NN)           // 24000

// fp32 param-pack offsets (elements)
#define P_EWRAW 0
#define P_SW    96000
#define P_SB    96128
#define P_LNG   96144
#define P_LNB   144144
#define P_C1W   192144
#define P_C1B   192656
#define P_BN1G  192688
#define P_BN1B  192720
#define P_BN1M  192752
#define P_BN1V  192784
#define P_C2W   192816
#define P_C2B   193072
#define P_BN2G  193080
#define P_BN2B  193088
#define P_BN2M  193096
#define P_BN2V  193104
#define P_FB1   193112
#define P_BF1G  193624
#define P_BF1B  194136
#define P_BF1M  194648
#define P_BF1V  195160
#define P_FW2   195672
#define P_FB2   261208
#define P_BF2G  261336
#define P_BF2B  261464
#define P_BF2M  261592
#define P_BF2V  261720
#define P_FOW   261848
#define P_FOB   263128
#define P_TOT   263138

// FC1 K-split: 24000 = 125 chunks x 192; 192 = 3 sub-steps x 64
#define KCH  192
#define NKC  125

__device__ __forceinline__ float b2f(unsigned short u) {
    union { unsigned int i; float f; } c;
    c.i = ((unsigned int)u) << 16;
    return c.f;
}

// ---------------------------------------------------------------------------
// K_prep: fused dtype sniffs + edge_index convert + histogram + x/param cvt.
// Each block computes both sniffs LOCALLY (no cross-block flag dependency);
// block 0 publishes flags[0] for later kernels.
struct PTab { const void* p[30]; };
__global__ __launch_bounds__(256)
void k_prep(const void* __restrict__ ei_raw, const unsigned int* __restrict__ ewr,
            const void* __restrict__ xr, PTab tab,
            int* __restrict__ ei32, int* __restrict__ cnt, int* __restrict__ flags,
            float* __restrict__ x32, float* __restrict__ P) {
    __shared__ int sh_is64, sh_bf;
    if (threadIdx.x == 0) {
        const int* pw = (const int*)ei_raw;
        int any = 0;
        #pragma unroll
        for (int i = 1; i < 32; i += 2) any |= pw[i];
        sh_is64 = (any == 0) ? 1 : 0;
        unsigned int w = ewr[0];
        sh_bf = ((w >> 16) == (w & 0xFFFFu)) ? 1 : 0;
        if (blockIdx.x == 0) flags[0] = sh_bf;
    }
    __syncthreads();
    int bf = sh_bf;
    long long gi = (long long)blockIdx.x * blockDim.x + threadIdx.x;
    if (gi < 2 * EE) {
        int i = (int)gi;
        int v = sh_is64 ? (int)((const long long*)ei_raw)[i]
                        : ((const int*)ei_raw)[i];
        ei32[i] = v;
        if (i >= EE) atomicAdd(&cnt[v], 1);   // col half
        return;
    }
    gi -= 2 * EE;
    if (gi < NN * BC) {
        int i = (int)gi;
        x32[i] = bf ? b2f(((const unsigned short*)xr)[i]) : ((const float*)xr)[i];
        return;
    }
    gi -= NN * BC;
    if (gi >= P_TOT) return;
    int i = (int)gi;
    const int off[31] = {
        P_EWRAW, P_SW, P_SB, P_LNG, P_LNB, P_C1W, P_C1B, P_BN1G, P_BN1B, P_BN1M,
        P_BN1V, P_C2W, P_C2B, P_BN2G, P_BN2B, P_BN2M, P_BN2V, P_FB1, P_BF1G,
        P_BF1B, P_BF1M, P_BF1V, P_FW2, P_FB2, P_BF2G, P_BF2B, P_BF2M, P_BF2V,
        P_FOW, P_FOB, P_TOT };
    int r = 0;
    #pragma unroll
    for (int j = 1; j < 31; ++j) r += (i >= off[j]) ? 1 : 0;
    int e = i - off[r];
    P[i] = bf ? b2f(((const unsigned short*)tab.p[r])[e])
              : ((const float*)tab.p[r])[e];
}

// K2: single-block exclusive scan over N=3000 counts
__global__ void k_scan(const int* __restrict__ cnt, int* __restrict__ off,
                       int* __restrict__ cursor) {
    __shared__ int part[1024];
    int t = threadIdx.x;
    int base = t * 3;
    int c0 = 0, c1 = 0, c2 = 0;
    if (base     < NN) c0 = cnt[base];
    if (base + 1 < NN) c1 = cnt[base + 1];
    if (base + 2 < NN) c2 = cnt[base + 2];
    int s = c0 + c1 + c2;
    part[t] = s;
    __syncthreads();
    for (int d = 1; d < 1024; d <<= 1) {
        int v = (t >= d) ? part[t - d] : 0;
        __syncthreads();
        part[t] += v;
        __syncthreads();
    }
    int excl = part[t] - s;
    if (base < NN)     { off[base]     = excl;           cursor[base]     = excl; }
    if (base + 1 < NN) { off[base + 1] = excl + c0;      cursor[base + 1] = excl + c0; }
    if (base + 2 < NN) { off[base + 2] = excl + c0 + c1; cursor[base + 2] = excl + c0 + c1; }
    if (t == 1023) off[NN] = part[1023];
}

// K3: scatter (row, sigmoid(w)) into CSR order
__global__ void k_scatter(const int* __restrict__ ei, const float* __restrict__ ew,
                          int* __restrict__ cursor,
                          int* __restrict__ rcsr, float* __restrict__ wcsr) {
    int e = blockIdx.x * blockDim.x + threadIdx.x;
    if (e < EE) {
        int p = atomicAdd(&cursor[ei[EE + e]], 1);
        rcsr[p] = ei[e];
        wcsr[p] = 1.f / (1.f + expf(-ew[e]));
    }
}

// K4: per-node scatter-mean + SAGE matmul + ReLU -> hb[b][n][m]
// 4-way edge unroll: 8 gather loads in flight per thread.
__global__ __launch_bounds__(256)
void k_agg_sage(const float* __restrict__ x,
                const int* __restrict__ off,
                const int* __restrict__ rcsr, const float* __restrict__ wcsr,
                const float* __restrict__ sw, const float* __restrict__ sb,
                float* __restrict__ hb) {
    __shared__ float aggL[BC];
    __shared__ float swL[CIN * MID];
    __shared__ float sbL[MID];
    int n = blockIdx.x;
    int t = threadIdx.x;
    if (t < CIN * MID) swL[t] = sw[t];
    if (t < MID)       sbL[t] = sb[t];
    int k0 = off[n], k1 = off[n + 1];
    float a0 = 0.f, a1 = 0.f, b0 = 0.f, b1 = 0.f;
    int k = k0;
    for (; k + 3 < k1; k += 4) {
        int   r0 = rcsr[k],     r1 = rcsr[k + 1];
        int   r2 = rcsr[k + 2], r3 = rcsr[k + 3];
        float w0 = wcsr[k],     w1 = wcsr[k + 1];
        float w2 = wcsr[k + 2], w3 = wcsr[k + 3];
        const float* xp0 = x + (size_t)r0 * BC;
        const float* xp1 = x + (size_t)r1 * BC;
        const float* xp2 = x + (size_t)r2 * BC;
        const float* xp3 = x + (size_t)r3 * BC;
        a0 += xp0[t]       * w0;  a1 += xp0[t + 256] * w0;
        b0 += xp1[t]       * w1;  b1 += xp1[t + 256] * w1;
        a0 += xp2[t]       * w2;  a1 += xp2[t + 256] * w2;
        b0 += xp3[t]       * w3;  b1 += xp3[t + 256] * w3;
    }
    for (; k < k1; ++k) {
        int r0 = rcsr[k];
        float w0 = wcsr[k];
        const float* xp0 = x + (size_t)r0 * BC;
        a0 += xp0[t] * w0;
        a1 += xp0[t + 256] * w0;
    }
    float inv = 1.f / fmaxf((float)(k1 - k0), 1.f);
    aggL[t]       = (a0 + b0) * inv;
    aggL[t + 256] = (a1 + b1) * inv;
    __syncthreads();
    #pragma unroll
    for (int r4 = 0; r4 < 4; ++r4) {
        int q = t + r4 * 256;
        int b = q >> 4, m = q & 15;
        float v = sbL[m];
        const float* ag = &aggL[b * CIN];
        #pragma unroll
        for (int c = 0; c < CIN; ++c) v += ag[c] * swL[c * MID + m];
        v = fmaxf(v, 0.f);
        hb[(size_t)b * HROW + n * MID + m] = v;
    }
}

// K5: LayerNorm stats per batch element
__global__ __launch_bounds__(256)
void k_ln_stats(const float* __restrict__ hb, float* __restrict__ stats) {
    __shared__ float ssum[256], ssq[256];
    int b = blockIdx.x, t = threadIdx.x;
    const float4* p = (const float4*)(hb + (size_t)b * HROW);
    float s = 0.f, q = 0.f;
    for (int i = t; i < HROW / 4; i += 256) {
        float4 v = p[i];
        s += v.x + v.y + v.z + v.w;
        q += v.x * v.x + v.y * v.y + v.z * v.z + v.w * v.w;
    }
    ssum[t] = s; ssq[t] = q;
    __syncthreads();
    for (int d = 128; d > 0; d >>= 1) {
        if (t < d) { ssum[t] += ssum[t + d]; ssq[t] += ssq[t + d]; }
        __syncthreads();
    }
    if (t == 0) {
        float mu = ssum[0] / (float)HROW;
        float var = ssq[0] / (float)HROW - mu * mu;
        stats[b]      = mu;
        stats[BB + b] = 1.f / sqrtf(var + EPSV);
    }
}

// K6: LN apply + conv1(+relu+bn1) + conv2(+relu+bn2) -> zT[k][b]
__global__ __launch_bounds__(256)
void k_conv_stack(const float* __restrict__ hb, const float* __restrict__ stats,
                  const float* __restrict__ P, float* __restrict__ zT) {
    __shared__ float hbt[64 * 65];
    __shared__ float w1s[G1 * MID], w2s[G2 * G1];
    __shared__ float c1s[G1], s1[G1], t1[G1];
    __shared__ float c2s[G2], s2[G2], t2[G2];
    int t = threadIdx.x;
    int n0 = blockIdx.x * 4;
    for (int j = t; j < G1 * MID; j += 256) w1s[j] = P[P_C1W + j];  // 512 > 256
    if (t < G2 * G1)  w2s[t] = P[P_C2W + t];
    if (t < G1) {
        float s = P[P_BN1G + t] / sqrtf(P[P_BN1V + t] + EPSV);
        c1s[t] = P[P_C1B + t]; s1[t] = s; t1[t] = P[P_BN1B + t] - P[P_BN1M + t] * s;
    }
    if (t < G2) {
        float s = P[P_BN2G + t] / sqrtf(P[P_BN2V + t] + EPSV);
        c2s[t] = P[P_C2B + t]; s2[t] = s; t2[t] = P[P_BN2B + t] - P[P_BN2M + t] * s;
    }
    #pragma unroll
    for (int r = 0; r < 4; ++r) {
        int i = r * 256 + t;
        int b = i >> 4, q = i & 15;
        float4 v = *(const float4*)(hb + (size_t)b * HROW + n0 * MID + q * 4);
        int ld = b * 65 + q * 4;
        hbt[ld] = v.x; hbt[ld + 1] = v.y; hbt[ld + 2] = v.z; hbt[ld + 3] = v.w;
    }
    __syncthreads();
    int nl = t >> 6, b = t & 63;
    int n = n0 + nl;
    float mu = stats[b], rs = stats[BB + b];
    float tv[MID];
    #pragma unroll
    for (int m = 0; m < MID; ++m) {
        float g = P[P_LNG + n * MID + m], lb = P[P_LNB + n * MID + m];
        tv[m] = (hbt[b * 65 + nl * MID + m] - mu) * rs * g + lb;
    }
    float v1[G1];
    #pragma unroll
    for (int o = 0; o < G1; ++o) {
        float d = c1s[o];
        #pragma unroll
        for (int m = 0; m < MID; ++m) d += w1s[o * MID + m] * tv[m];
        d = fmaxf(d, 0.f);
        v1[o] = d * s1[o] + t1[o];
    }
    #pragma unroll
    for (int o2 = 0; o2 < G2; ++o2) {
        float d = c2s[o2];
        #pragma unroll
        for (int c = 0; c < G1; ++c) d += w2s[o2 * G1 + c] * v1[c];
        d = fmaxf(d, 0.f);
        zT[((size_t)(o2 * NN + n)) * BB + b] = d * s2[o2] + t2[o2];
    }
}

// K7: FC1 partial GEMM — scalar-w design (R6: LDS-staged version was
// LDS-traffic-bound at ~3 B/FMA = 34 µs floor + 768K conflict cycles).
// lane = b (64 lanes = full batch), z[64 k] in VGPRs (coalesced dword loads),
// w addresses wave-uniform (readfirstlane) -> compiler emits s_load (SMEM/K$,
// zero VMEM, zero LDS); FMA = v_fmac_f32 vgpr, sgpr, vgpr.
// Grid (4 fg x 125 kc) = 500 blocks x 4 waves; wave handles 32 f x 192 k.
__global__ __launch_bounds__(256)
void k_fc1(const float* __restrict__ zT, const void* __restrict__ w1raw,
           const int* __restrict__ flags, float* __restrict__ out1p) {
    int kc = blockIdx.y;
    int wv = __builtin_amdgcn_readfirstlane(threadIdx.x >> 6);
    int lane = threadIdx.x & 63;
    int fbase = blockIdx.x * 128 + wv * 32;
    int kcb = kc * KCH;
    float acc[32];
    #pragma unroll
    for (int f = 0; f < 32; ++f) acc[f] = 0.f;
    if (flags[0]) {
        const unsigned int* wb = (const unsigned int*)w1raw;  // packed bf16 pairs
        for (int ss = 0; ss < KCH / 64; ++ss) {
            int k0 = kcb + ss * 64;
            float z[64];
            #pragma unroll
            for (int j = 0; j < 64; ++j) z[j] = zT[(size_t)(k0 + j) * BB + lane];
            #pragma unroll
            for (int f = 0; f < 32; ++f) {
                const unsigned int* wr = wb + ((size_t)(fbase + f) * D0 + k0) / 2;
                #pragma unroll
                for (int j = 0; j < 32; ++j) {
                    unsigned int u = wr[j];
                    acc[f] += b2f((unsigned short)(u & 0xFFFFu)) * z[2 * j]
                            + b2f((unsigned short)(u >> 16))     * z[2 * j + 1];
                }
            }
        }
    } else {
        const float* wf = (const float*)w1raw;
        for (int ss = 0; ss < KCH / 64; ++ss) {
            int k0 = kcb + ss * 64;
            float z[64];
            #pragma unroll
            for (int j = 0; j < 64; ++j) z[j] = zT[(size_t)(k0 + j) * BB + lane];
            #pragma unroll
            for (int f = 0; f < 32; ++f) {
                const float* wr = wf + (size_t)(fbase + f) * D0 + k0;
                #pragma unroll
                for (int j = 0; j < 64; ++j) acc[f] += wr[j] * z[j];
            }
        }
    }
    float* op = out1p + ((size_t)kc * FC1N + fbase) * BB + lane;
    #pragma unroll
    for (int f = 0; f < 32; ++f) op[f * BB] = acc[f];   // lane-coalesced
}

// K8: FC1 reduce partials + bias + bn + relu
__global__ void k_fc1_fin(const float* __restrict__ out1p, const float* __restrict__ P,
                          float* __restrict__ z1) {
    int i = blockIdx.x * blockDim.x + threadIdx.x;
    if (i < BB * FC1N) {
        int f = i >> 6, b = i & 63;
        float acc = 0.f;
        for (int kc = 0; kc < NKC; ++kc)
            acc += out1p[((size_t)kc * FC1N + f) * BB + b];
        acc += P[P_FB1 + f];
        float s = P[P_BF1G + f] / sqrtf(P[P_BF1V + f] + EPSV);
        acc = (acc - P[P_BF1M + f]) * s + P[P_BF1B + f];
        z1[b * FC1N + f] = fmaxf(acc, 0.f);
    }
}

// K9: fused FC2(+bn+relu) + head + softmax; one block per batch element.
__global__ __launch_bounds__(128)
void k_fc2head(const float* __restrict__ z1, const float* __restrict__ P,
               const int* __restrict__ flags, void* __restrict__ outv) {
    __shared__ float zsrc[FC1N];
    __shared__ float z2s[FC2N];
    __shared__ float lg[OUTN];
    __shared__ float red[2];
    int b = blockIdx.x, t = threadIdx.x;
    #pragma unroll
    for (int r = 0; r < 4; ++r) zsrc[t + r * 128] = z1[b * FC1N + t + r * 128];
    __syncthreads();
    {
        int f = t;
        const float4* wr = (const float4*)(P + P_FW2 + (size_t)f * FC1N);
        const float4* zr = (const float4*)zsrc;
        float acc = P[P_FB2 + f];
        for (int k = 0; k < FC1N / 4; ++k) {
            float4 wv = wr[k];
            float4 zv = zr[k];
            acc += wv.x * zv.x + wv.y * zv.y + wv.z * zv.z + wv.w * zv.w;
        }
        float s = P[P_BF2G + f] / sqrtf(P[P_BF2V + f] + EPSV);
        acc = (acc - P[P_BF2M + f]) * s + P[P_BF2B + f];
        z2s[f] = fmaxf(acc, 0.f);
    }
    __syncthreads();
    if (t < OUTN) {
        float acc = P[P_FOB + t];
        const float* wr = P + P_FOW + t * FC2N;
        for (int k = 0; k < FC2N; ++k) acc += wr[k] * z2s[k];
        lg[t] = acc;
    }
    __syncthreads();
    if (t == 0) {
        float mx = lg[0];
        for (int o = 1; o < OUTN; ++o) mx = fmaxf(mx, lg[o]);
        float s = 0.f;
        for (int o = 0; o < OUTN; ++o) s += expf(lg[o] - mx);
        red[0] = mx; red[1] = s;
    }
    __syncthreads();
    if (t < OUTN) {
        float p = expf(lg[t] - red[0]) / red[1];
        if (flags[0]) {
            __hip_bfloat16* o = (__hip_bfloat16*)outv;
            o[b * OUTN + t] = __float2bfloat16(p);
            o[BB * OUTN + b * OUTN + t] = __float2bfloat16(lg[t]);
        } else {
            float* o = (float*)outv;
            o[b * OUTN + t] = p;
            o[BB * OUTN + b * OUTN + t] = lg[t];
        }
    }
}

// ---------------------------------------------------------------------------
extern "C" void kernel_launch(void* const* d_in, const int* in_sizes, int n_in,
                              void* d_out, int out_size, void* d_ws, size_t ws_size,
                              hipStream_t stream) {
    char* ws = (char*)d_ws;
    size_t o = 0;
    auto carve = [&](size_t bytes) { void* p = ws + o; o += (bytes + 255) & ~(size_t)255; return p; };
    int*   flags  = (int*)  carve(16);
    int*   ei32   = (int*)  carve((size_t)2 * EE * sizeof(int));
    int*   cnt    = (int*)  carve(NN * sizeof(int));
    int*   off    = (int*)  carve((NN + 1) * sizeof(int));
    int*   cursor = (int*)  carve(NN * sizeof(int));
    int*   rcsr   = (int*)  carve(EE * sizeof(int));
    float* wcsr   = (float*)carve(EE * sizeof(float));
    float* P      = (float*)carve((size_t)P_TOT * sizeof(float));
    float* x32    = (float*)carve((size_t)NN * BC * sizeof(float));
    float* hb     = (float*)carve((size_t)BB * HROW * sizeof(float));
    float* stats  = (float*)carve(2 * BB * sizeof(float));
    float* zT     = (float*)carve((size_t)D0 * BB * sizeof(float));
    float* out1p  = (float*)carve((size_t)NKC * FC1N * BB * sizeof(float));
    float* z1     = (float*)carve(BB * FC1N * sizeof(float));

    hipMemsetAsync(cnt, 0, NN * sizeof(int), stream);

    PTab tab;
    tab.p[0]  = d_in[2];   tab.p[1]  = d_in[4];   tab.p[2]  = d_in[5];
    tab.p[3]  = d_in[6];   tab.p[4]  = d_in[7];   tab.p[5]  = d_in[8];
    tab.p[6]  = d_in[9];   tab.p[7]  = d_in[10];  tab.p[8]  = d_in[11];
    tab.p[9]  = d_in[12];  tab.p[10] = d_in[13];  tab.p[11] = d_in[14];
    tab.p[12] = d_in[15];  tab.p[13] = d_in[16];  tab.p[14] = d_in[17];
    tab.p[15] = d_in[18];  tab.p[16] = d_in[19];  tab.p[17] = d_in[21];
    tab.p[18] = d_in[22];  tab.p[19] = d_in[23];  tab.p[20] = d_in[24];
    tab.p[21] = d_in[25];  tab.p[22] = d_in[26];  tab.p[23] = d_in[27];
    tab.p[24] = d_in[28];  tab.p[25] = d_in[29];  tab.p[26] = d_in[30];
    tab.p[27] = d_in[31];  tab.p[28] = d_in[32];  tab.p[29] = d_in[33];

    long long prep_tot = 2LL * EE + (long long)NN * BC + P_TOT;
    k_prep<<<(int)((prep_tot + 255) / 256), 256, 0, stream>>>(
        d_in[1], (const unsigned int*)d_in[2], d_in[0], tab,
        ei32, cnt, flags, x32, P);

    k_scan   <<<1, 1024, 0, stream>>>(cnt, off, cursor);
    k_scatter<<<(EE + 255) / 256, 256, 0, stream>>>(ei32, P + P_EWRAW, cursor, rcsr, wcsr);
    k_agg_sage<<<NN, 256, 0, stream>>>(x32, off, rcsr, wcsr, P + P_SW, P + P_SB, hb);
    k_ln_stats<<<BB, 256, 0, stream>>>(hb, stats);
    k_conv_stack<<<NN / 4, 256, 0, stream>>>(hb, stats, P, zT);
    dim3 g7(4, NKC);
    k_fc1    <<<g7, 256, 0, stream>>>(zT, d_in[20], flags, out1p);
    k_fc1_fin<<<(BB * FC1N + 255) / 256, 256, 0, stream>>>(out1p, P, z1);
    k_fc2head<<<BB, 128, 0, stream>>>(z1, P, flags, (void*)d_out);
}

// Round 8
// 265.995 us; speedup vs baseline: 1.6416x; 1.6416x over previous
//
#include <hip/hip_runtime.h>
#include <hip/hip_bf16.h>
#include <math.h>

// Problem constants
#define NN   3000
#define EE   96000
#define BB   64
#define CIN  8
#define MID  16
#define G1   32
#define G2   8
#define FC1N 512
#define FC2N 128
#define OUTN 10
#define EPSV 1e-5f

#define BC   (BB * CIN)          // 512
#define HROW (NN * MID)          // 48000 floats per batch row of hb
#define D0   (G2 * NN)           // 24000

// fp32 param-pack offsets (elements)
#define P_EWRAW 0
#define P_SW    96000
#define P_SB    96128
#define P_LNG   96144
#define P_LNB   144144
#define P_C1W   192144
#define P_C1B   192656
#define P_BN1G  192688
#define P_BN1B  192720
#define P_BN1M  192752
#define P_BN1V  192784
#define P_C2W   192816
#define P_C2B   193072
#define P_BN2G  193080
#define P_BN2B  193088
#define P_BN2M  193096
#define P_BN2V  193104
#define P_FB1   193112
#define P_BF1G  193624
#define P_BF1B  194136
#define P_BF1M  194648
#define P_BF1V  195160
#define P_FW2   195672
#define P_FB2   261208
#define P_BF2G  261336
#define P_BF2B  261464
#define P_BF2M  261592
#define P_BF2V  261720
#define P_FOW   261848
#define P_FOB   263128
#define P_TOT   263138

// FC1 K-split: 24000 = 75 chunks x 320; each chunk = 10 MFMA K-steps of 32
#define KCH  320
#define NKC  75

__device__ __forceinline__ float b2f(unsigned short u) {
    union { unsigned int i; float f; } c;
    c.i = ((unsigned int)u) << 16;
    return c.f;
}

__device__ __forceinline__ unsigned short f2b_rne(float x) {
    union { float f; unsigned int u; } c; c.f = x;
    unsigned int r = c.u + 0x7FFFu + ((c.u >> 16) & 1u);
    return (unsigned short)(r >> 16);
}

typedef __attribute__((ext_vector_type(8))) short short8;   // 8 bf16 (4 VGPRs)
typedef __attribute__((ext_vector_type(4))) float f32x4;

// ---------------------------------------------------------------------------
// K_prep: fused dtype sniffs + edge_index convert + histogram + x/param cvt.
struct PTab { const void* p[30]; };
__global__ __launch_bounds__(256)
void k_prep(const void* __restrict__ ei_raw, const unsigned int* __restrict__ ewr,
            const void* __restrict__ xr, PTab tab,
            int* __restrict__ ei32, int* __restrict__ cnt, int* __restrict__ flags,
            float* __restrict__ x32, float* __restrict__ P) {
    __shared__ int sh_is64, sh_bf;
    if (threadIdx.x == 0) {
        const int* pw = (const int*)ei_raw;
        int any = 0;
        #pragma unroll
        for (int i = 1; i < 32; i += 2) any |= pw[i];
        sh_is64 = (any == 0) ? 1 : 0;
        unsigned int w = ewr[0];
        sh_bf = ((w >> 16) == (w & 0xFFFFu)) ? 1 : 0;
        if (blockIdx.x == 0) flags[0] = sh_bf;
    }
    __syncthreads();
    int bf = sh_bf;
    long long gi = (long long)blockIdx.x * blockDim.x + threadIdx.x;
    if (gi < 2 * EE) {
        int i = (int)gi;
        int v = sh_is64 ? (int)((const long long*)ei_raw)[i]
                        : ((const int*)ei_raw)[i];
        ei32[i] = v;
        if (i >= EE) atomicAdd(&cnt[v], 1);   // col half
        return;
    }
    gi -= 2 * EE;
    if (gi < NN * BC) {
        int i = (int)gi;
        x32[i] = bf ? b2f(((const unsigned short*)xr)[i]) : ((const float*)xr)[i];
        return;
    }
    gi -= NN * BC;
    if (gi >= P_TOT) return;
    int i = (int)gi;
    const int off[31] = {
        P_EWRAW, P_SW, P_SB, P_LNG, P_LNB, P_C1W, P_C1B, P_BN1G, P_BN1B, P_BN1M,
        P_BN1V, P_C2W, P_C2B, P_BN2G, P_BN2B, P_BN2M, P_BN2V, P_FB1, P_BF1G,
        P_BF1B, P_BF1M, P_BF1V, P_FW2, P_FB2, P_BF2G, P_BF2B, P_BF2M, P_BF2V,
        P_FOW, P_FOB, P_TOT };
    int r = 0;
    #pragma unroll
    for (int j = 1; j < 31; ++j) r += (i >= off[j]) ? 1 : 0;
    int e = i - off[r];
    P[i] = bf ? b2f(((const unsigned short*)tab.p[r])[e])
              : ((const float*)tab.p[r])[e];
}

// K2: single-block exclusive scan over N=3000 counts
__global__ void k_scan(const int* __restrict__ cnt, int* __restrict__ off,
                       int* __restrict__ cursor) {
    __shared__ int part[1024];
    int t = threadIdx.x;
    int base = t * 3;
    int c0 = 0, c1 = 0, c2 = 0;
    if (base     < NN) c0 = cnt[base];
    if (base + 1 < NN) c1 = cnt[base + 1];
    if (base + 2 < NN) c2 = cnt[base + 2];
    int s = c0 + c1 + c2;
    part[t] = s;
    __syncthreads();
    for (int d = 1; d < 1024; d <<= 1) {
        int v = (t >= d) ? part[t - d] : 0;
        __syncthreads();
        part[t] += v;
        __syncthreads();
    }
    int excl = part[t] - s;
    if (base < NN)     { off[base]     = excl;           cursor[base]     = excl; }
    if (base + 1 < NN) { off[base + 1] = excl + c0;      cursor[base + 1] = excl + c0; }
    if (base + 2 < NN) { off[base + 2] = excl + c0 + c1; cursor[base + 2] = excl + c0 + c1; }
    if (t == 1023) off[NN] = part[1023];
}

// K3: scatter (row, sigmoid(w)) into CSR order
__global__ void k_scatter(const int* __restrict__ ei, const float* __restrict__ ew,
                          int* __restrict__ cursor,
                          int* __restrict__ rcsr, float* __restrict__ wcsr) {
    int e = blockIdx.x * blockDim.x + threadIdx.x;
    if (e < EE) {
        int p = atomicAdd(&cursor[ei[EE + e]], 1);
        rcsr[p] = ei[e];
        wcsr[p] = 1.f / (1.f + expf(-ew[e]));
    }
}

// K4: per-node scatter-mean + SAGE matmul + ReLU -> hb[b][n][m]
__global__ __launch_bounds__(256)
void k_agg_sage(const float* __restrict__ x,
                const int* __restrict__ off,
                const int* __restrict__ rcsr, const float* __restrict__ wcsr,
                const float* __restrict__ sw, const float* __restrict__ sb,
                float* __restrict__ hb) {
    __shared__ float aggL[BC];
    __shared__ float swL[CIN * MID];
    __shared__ float sbL[MID];
    int n = blockIdx.x;
    int t = threadIdx.x;
    if (t < CIN * MID) swL[t] = sw[t];
    if (t < MID)       sbL[t] = sb[t];
    int k0 = off[n], k1 = off[n + 1];
    float a0 = 0.f, a1 = 0.f, b0 = 0.f, b1 = 0.f;
    int k = k0;
    for (; k + 3 < k1; k += 4) {
        int   r0 = rcsr[k],     r1 = rcsr[k + 1];
        int   r2 = rcsr[k + 2], r3 = rcsr[k + 3];
        float w0 = wcsr[k],     w1 = wcsr[k + 1];
        float w2 = wcsr[k + 2], w3 = wcsr[k + 3];
        const float* xp0 = x + (size_t)r0 * BC;
        const float* xp1 = x + (size_t)r1 * BC;
        const float* xp2 = x + (size_t)r2 * BC;
        const float* xp3 = x + (size_t)r3 * BC;
        a0 += xp0[t]       * w0;  a1 += xp0[t + 256] * w0;
        b0 += xp1[t]       * w1;  b1 += xp1[t + 256] * w1;
        a0 += xp2[t]       * w2;  a1 += xp2[t + 256] * w2;
        b0 += xp3[t]       * w3;  b1 += xp3[t + 256] * w3;
    }
    for (; k < k1; ++k) {
        int r0 = rcsr[k];
        float w0 = wcsr[k];
        const float* xp0 = x + (size_t)r0 * BC;
        a0 += xp0[t] * w0;
        a1 += xp0[t + 256] * w0;
    }
    float inv = 1.f / fmaxf((float)(k1 - k0), 1.f);
    aggL[t]       = (a0 + b0) * inv;
    aggL[t + 256] = (a1 + b1) * inv;
    __syncthreads();
    #pragma unroll
    for (int r4 = 0; r4 < 4; ++r4) {
        int q = t + r4 * 256;
        int b = q >> 4, m = q & 15;
        float v = sbL[m];
        const float* ag = &aggL[b * CIN];
        #pragma unroll
        for (int c = 0; c < CIN; ++c) v += ag[c] * swL[c * MID + m];
        v = fmaxf(v, 0.f);
        hb[(size_t)b * HROW + n * MID + m] = v;
    }
}

// K5: LayerNorm stats per batch element
__global__ __launch_bounds__(256)
void k_ln_stats(const float* __restrict__ hb, float* __restrict__ stats) {
    __shared__ float ssum[256], ssq[256];
    int b = blockIdx.x, t = threadIdx.x;
    const float4* p = (const float4*)(hb + (size_t)b * HROW);
    float s = 0.f, q = 0.f;
    for (int i = t; i < HROW / 4; i += 256) {
        float4 v = p[i];
        s += v.x + v.y + v.z + v.w;
        q += v.x * v.x + v.y * v.y + v.z * v.z + v.w * v.w;
    }
    ssum[t] = s; ssq[t] = q;
    __syncthreads();
    for (int d = 128; d > 0; d >>= 1) {
        if (t < d) { ssum[t] += ssum[t + d]; ssq[t] += ssq[t + d]; }
        __syncthreads();
    }
    if (t == 0) {
        float mu = ssum[0] / (float)HROW;
        float var = ssq[0] / (float)HROW - mu * mu;
        stats[b]      = mu;
        stats[BB + b] = 1.f / sqrtf(var + EPSV);
    }
}

// K6: LN apply + conv1(+relu+bn1) + conv2(+relu+bn2) -> zT[k][b]
__global__ __launch_bounds__(256)
void k_conv_stack(const float* __restrict__ hb, const float* __restrict__ stats,
                  const float* __restrict__ P, float* __restrict__ zT) {
    __shared__ float hbt[64 * 65];
    __shared__ float w1s[G1 * MID], w2s[G2 * G1];
    __shared__ float c1s[G1], s1[G1], t1[G1];
    __shared__ float c2s[G2], s2[G2], t2[G2];
    int t = threadIdx.x;
    int n0 = blockIdx.x * 4;
    for (int j = t; j < G1 * MID; j += 256) w1s[j] = P[P_C1W + j];  // 512 > 256
    if (t < G2 * G1)  w2s[t] = P[P_C2W + t];
    if (t < G1) {
        float s = P[P_BN1G + t] / sqrtf(P[P_BN1V + t] + EPSV);
        c1s[t] = P[P_C1B + t]; s1[t] = s; t1[t] = P[P_BN1B + t] - P[P_BN1M + t] * s;
    }
    if (t < G2) {
        float s = P[P_BN2G + t] / sqrtf(P[P_BN2V + t] + EPSV);
        c2s[t] = P[P_C2B + t]; s2[t] = s; t2[t] = P[P_BN2B + t] - P[P_BN2M + t] * s;
    }
    #pragma unroll
    for (int r = 0; r < 4; ++r) {
        int i = r * 256 + t;
        int b = i >> 4, q = i & 15;
        float4 v = *(const float4*)(hb + (size_t)b * HROW + n0 * MID + q * 4);
        int ld = b * 65 + q * 4;
        hbt[ld] = v.x; hbt[ld + 1] = v.y; hbt[ld + 2] = v.z; hbt[ld + 3] = v.w;
    }
    __syncthreads();
    int nl = t >> 6, b = t & 63;
    int n = n0 + nl;
    float mu = stats[b], rs = stats[BB + b];
    float tv[MID];
    #pragma unroll
    for (int m = 0; m < MID; ++m) {
        float g = P[P_LNG + n * MID + m], lb = P[P_LNB + n * MID + m];
        tv[m] = (hbt[b * 65 + nl * MID + m] - mu) * rs * g + lb;
    }
    float v1[G1];
    #pragma unroll
    for (int o = 0; o < G1; ++o) {
        float d = c1s[o];
        #pragma unroll
        for (int m = 0; m < MID; ++m) d += w1s[o * MID + m] * tv[m];
        d = fmaxf(d, 0.f);
        v1[o] = d * s1[o] + t1[o];
    }
    #pragma unroll
    for (int o2 = 0; o2 < G2; ++o2) {
        float d = c2s[o2];
        #pragma unroll
        for (int c = 0; c < G1; ++c) d += w2s[o2 * G1 + c] * v1[c];
        d = fmaxf(d, 0.f);
        zT[((size_t)(o2 * NN + n)) * BB + b] = d * s2[o2] + t2[o2];
    }
}

// K7: FC1 partial GEMM via MFMA bf16 (R7 post-mortem: SMEM streaming failed;
// R6 LDS version was LDS-traffic-bound at 3 B/FMA). C[512f][64b]=W·Z, both
// operands cvt to bf16 (RNE). Block = 4 waves = 64f x 64b tile; per 32-k step:
// wave loads A-frag from global w1 (lane&15=f-row, quad=k-group; 4 lanes/row
// = 128 B contiguous), z staged block-wide into LDS TRANSPOSED as packed bf16
// zs[b][k] (stride 80 B -> b128-aligned, 2-way banks = free) so each B-frag
// is one ds_read_b128. 4 MFMA/wave/step. Floors: HBM 49 MB ~ 8 us; MFMA 0.7 us.
__global__ __launch_bounds__(256)
void k_fc1(const float* __restrict__ zT, const void* __restrict__ w1raw,
           const int* __restrict__ flags, float* __restrict__ out1p) {
    __shared__ unsigned int zs[64 * 20];   // [b][k-pair], row = 20 u32 = 80 B
    int kc = blockIdx.y;
    int t = threadIdx.x;
    int lane = t & 63;
    int wv = t >> 6;
    int n = lane & 15;           // f-row in A, b-col in B/D
    int q = lane >> 4;           // quad: k-group in A/B, row-group in D
    int fbase = blockIdx.x * 64 + wv * 16;
    int bf = flags[0];
    const size_t kcb = (size_t)kc * KCH;
    const float*          w1f = (const float*)w1raw;
    const unsigned short* w1b = (const unsigned short*)w1raw;

    f32x4 acc0 = {0.f, 0.f, 0.f, 0.f};
    f32x4 acc1 = {0.f, 0.f, 0.f, 0.f};
    f32x4 acc2 = {0.f, 0.f, 0.f, 0.f};
    f32x4 acc3 = {0.f, 0.f, 0.f, 0.f};

    int zb = t & 63;             // staging: b
    int kg = t >> 6;             // staging: k-group (0..3)

    for (int ks = 0; ks < KCH / 32; ++ks) {
        size_t k0 = kcb + (size_t)ks * 32;
        // ---- stage z tile (32k x 64b) transposed as packed bf16 ----
        const float* zsrc = zT + k0 * BB + zb;
        float zv[8];
        #pragma unroll
        for (int j = 0; j < 8; ++j) zv[j] = zsrc[(kg * 8 + j) * BB];  // coalesced per instr
        unsigned int pk0 = (unsigned int)f2b_rne(zv[0]) | ((unsigned int)f2b_rne(zv[1]) << 16);
        unsigned int pk1 = (unsigned int)f2b_rne(zv[2]) | ((unsigned int)f2b_rne(zv[3]) << 16);
        unsigned int pk2 = (unsigned int)f2b_rne(zv[4]) | ((unsigned int)f2b_rne(zv[5]) << 16);
        unsigned int pk3 = (unsigned int)f2b_rne(zv[6]) | ((unsigned int)f2b_rne(zv[7]) << 16);
        __syncthreads();   // previous step's reads done before overwrite
        *(uint4*)&zs[zb * 20 + kg * 4] = make_uint4(pk0, pk1, pk2, pk3);
        // ---- A fragment from global (no LDS) ----
        short8 av;
        if (bf) {
            av = *(const short8*)(w1b + (size_t)(fbase + n) * D0 + k0 + q * 8);
        } else {
            const float* wr = w1f + (size_t)(fbase + n) * D0 + k0 + q * 8;
            float4 wa = *(const float4*)wr;
            float4 wb = *(const float4*)(wr + 4);
            av[0] = (short)f2b_rne(wa.x); av[1] = (short)f2b_rne(wa.y);
            av[2] = (short)f2b_rne(wa.z); av[3] = (short)f2b_rne(wa.w);
            av[4] = (short)f2b_rne(wb.x); av[5] = (short)f2b_rne(wb.y);
            av[6] = (short)f2b_rne(wb.z); av[7] = (short)f2b_rne(wb.w);
        }
        __syncthreads();   // zs ready
        // ---- 4 B-frags (one per 16-b tile) + MFMA ----
        const char* zbase = (const char*)zs + q * 16;
        short8 bv0 = *(const short8*)(zbase + (0  + n) * 80);
        short8 bv1 = *(const short8*)(zbase + (16 + n) * 80);
        short8 bv2 = *(const short8*)(zbase + (32 + n) * 80);
        short8 bv3 = *(const short8*)(zbase + (48 + n) * 80);
        acc0 = __builtin_amdgcn_mfma_f32_16x16x32_bf16(av, bv0, acc0, 0, 0, 0);
        acc1 = __builtin_amdgcn_mfma_f32_16x16x32_bf16(av, bv1, acc1, 0, 0, 0);
        acc2 = __builtin_amdgcn_mfma_f32_16x16x32_bf16(av, bv2, acc2, 0, 0, 0);
        acc3 = __builtin_amdgcn_mfma_f32_16x16x32_bf16(av, bv3, acc3, 0, 0, 0);
    }
    // ---- store D: lane holds D[fbase + q*4 + r][b0 + n], r = 0..3 ----
    float* op = out1p + ((size_t)kc * FC1N + fbase + q * 4) * BB + n;
    #pragma unroll
    for (int r = 0; r < 4; ++r) {
        op[r * BB +  0] = acc0[r];
        op[r * BB + 16] = acc1[r];
        op[r * BB + 32] = acc2[r];
        op[r * BB + 48] = acc3[r];
    }
}

// K8: FC1 reduce partials + bias + bn + relu
__global__ void k_fc1_fin(const float* __restrict__ out1p, const float* __restrict__ P,
                          float* __restrict__ z1) {
    int i = blockIdx.x * blockDim.x + threadIdx.x;
    if (i < BB * FC1N) {
        int f = i >> 6, b = i & 63;
        float acc = 0.f;
        for (int kc = 0; kc < NKC; ++kc)
            acc += out1p[((size_t)kc * FC1N + f) * BB + b];
        acc += P[P_FB1 + f];
        float s = P[P_BF1G + f] / sqrtf(P[P_BF1V + f] + EPSV);
        acc = (acc - P[P_BF1M + f]) * s + P[P_BF1B + f];
        z1[b * FC1N + f] = fmaxf(acc, 0.f);
    }
}

// K9: fused FC2(+bn+relu) + head + softmax; one block per batch element.
__global__ __launch_bounds__(128)
void k_fc2head(const float* __restrict__ z1, const float* __restrict__ P,
               const int* __restrict__ flags, void* __restrict__ outv) {
    __shared__ float zsrc[FC1N];
    __shared__ float z2s[FC2N];
    __shared__ float lg[OUTN];
    __shared__ float red[2];
    int b = blockIdx.x, t = threadIdx.x;
    #pragma unroll
    for (int r = 0; r < 4; ++r) zsrc[t + r * 128] = z1[b * FC1N + t + r * 128];
    __syncthreads();
    {
        int f = t;
        const float4* wr = (const float4*)(P + P_FW2 + (size_t)f * FC1N);
        const float4* zr = (const float4*)zsrc;
        float acc = P[P_FB2 + f];
        for (int k = 0; k < FC1N / 4; ++k) {
            float4 wv = wr[k];
            float4 zv = zr[k];
            acc += wv.x * zv.x + wv.y * zv.y + wv.z * zv.z + wv.w * zv.w;
        }
        float s = P[P_BF2G + f] / sqrtf(P[P_BF2V + f] + EPSV);
        acc = (acc - P[P_BF2M + f]) * s + P[P_BF2B + f];
        z2s[f] = fmaxf(acc, 0.f);
    }
    __syncthreads();
    if (t < OUTN) {
        float acc = P[P_FOB + t];
        const float* wr = P + P_FOW + t * FC2N;
        for (int k = 0; k < FC2N; ++k) acc += wr[k] * z2s[k];
        lg[t] = acc;
    }
    __syncthreads();
    if (t == 0) {
        float mx = lg[0];
        for (int o = 1; o < OUTN; ++o) mx = fmaxf(mx, lg[o]);
        float s = 0.f;
        for (int o = 0; o < OUTN; ++o) s += expf(lg[o] - mx);
        red[0] = mx; red[1] = s;
    }
    __syncthreads();
    if (t < OUTN) {
        float p = expf(lg[t] - red[0]) / red[1];
        if (flags[0]) {
            __hip_bfloat16* o = (__hip_bfloat16*)outv;
            o[b * OUTN + t] = __float2bfloat16(p);
            o[BB * OUTN + b * OUTN + t] = __float2bfloat16(lg[t]);
        } else {
            float* o = (float*)outv;
            o[b * OUTN + t] = p;
            o[BB * OUTN + b * OUTN + t] = lg[t];
        }
    }
}

// ---------------------------------------------------------------------------
extern "C" void kernel_launch(void* const* d_in, const int* in_sizes, int n_in,
                              void* d_out, int out_size, void* d_ws, size_t ws_size,
                              hipStream_t stream) {
    char* ws = (char*)d_ws;
    size_t o = 0;
    auto carve = [&](size_t bytes) { void* p = ws + o; o += (bytes + 255) & ~(size_t)255; return p; };
    int*   flags  = (int*)  carve(16);
    int*   ei32   = (int*)  carve((size_t)2 * EE * sizeof(int));
    int*   cnt    = (int*)  carve(NN * sizeof(int));
    int*   off    = (int*)  carve((NN + 1) * sizeof(int));
    int*   cursor = (int*)  carve(NN * sizeof(int));
    int*   rcsr   = (int*)  carve(EE * sizeof(int));
    float* wcsr   = (float*)carve(EE * sizeof(float));
    float* P      = (float*)carve((size_t)P_TOT * sizeof(float));
    float* x32    = (float*)carve((size_t)NN * BC * sizeof(float));
    float* hb     = (float*)carve((size_t)BB * HROW * sizeof(float));
    float* stats  = (float*)carve(2 * BB * sizeof(float));
    float* zT     = (float*)carve((size_t)D0 * BB * sizeof(float));
    float* out1p  = (float*)carve((size_t)NKC * FC1N * BB * sizeof(float));
    float* z1     = (float*)carve(BB * FC1N * sizeof(float));

    hipMemsetAsync(cnt, 0, NN * sizeof(int), stream);

    PTab tab;
    tab.p[0]  = d_in[2];   tab.p[1]  = d_in[4];   tab.p[2]  = d_in[5];
    tab.p[3]  = d_in[6];   tab.p[4]  = d_in[7];   tab.p[5]  = d_in[8];
    tab.p[6]  = d_in[9];   tab.p[7]  = d_in[10];  tab.p[8]  = d_in[11];
    tab.p[9]  = d_in[12];  tab.p[10] = d_in[13];  tab.p[11] = d_in[14];
    tab.p[12] = d_in[15];  tab.p[13] = d_in[16];  tab.p[14] = d_in[17];
    tab.p[15] = d_in[18];  tab.p[16] = d_in[19];  tab.p[17] = d_in[21];
    tab.p[18] = d_in[22];  tab.p[19] = d_in[23];  tab.p[20] = d_in[24];
    tab.p[21] = d_in[25];  tab.p[22] = d_in[26];  tab.p[23] = d_in[27];
    tab.p[24] = d_in[28];  tab.p[25] = d_in[29];  tab.p[26] = d_in[30];
    tab.p[27] = d_in[31];  tab.p[28] = d_in[32];  tab.p[29] = d_in[33];

    long long prep_tot = 2LL * EE + (long long)NN * BC + P_TOT;
    k_prep<<<(int)((prep_tot + 255) / 256), 256, 0, stream>>>(
        d_in[1], (const unsigned int*)d_in[2], d_in[0], tab,
        ei32, cnt, flags, x32, P);

    k_scan   <<<1, 1024, 0, stream>>>(cnt, off, cursor);
    k_scatter<<<(EE + 255) / 256, 256, 0, stream>>>(ei32, P + P_EWRAW, cursor, rcsr, wcsr);
    k_agg_sage<<<NN, 256, 0, stream>>>(x32, off, rcsr, wcsr, P + P_SW, P + P_SB, hb);
    k_ln_stats<<<BB, 256, 0, stream>>>(hb, stats);
    k_conv_stack<<<NN / 4, 256, 0, stream>>>(hb, stats, P, zT);
    dim3 g7(FC1N / 64, NKC);
    k_fc1    <<<g7, 256, 0, stream>>>(zT, d_in[20], flags, out1p);
    k_fc1_fin<<<(BB * FC1N + 255) / 256, 256, 0, stream>>>(out1p, P, z1);
    k_fc2head<<<BB, 128, 0, stream>>>(z1, P, flags, (void*)d_out);
}

// Round 9
// 259.778 us; speedup vs baseline: 1.6809x; 1.0239x over previous
//
#include <hip/hip_runtime.h>
#include <hip/hip_bf16.h>
#include <math.h>

// Problem constants
#define NN   3000
#define EE   96000
#define BB   64
#define CIN  8
#define MID  16
#define G1   32
#define G2   8
#define FC1N 512
#define FC2N 128
#define OUTN 10
#define EPSV 1e-5f

#define BC   (BB * CIN)          // 512
#define HROW (NN * MID)          // 48000 floats per batch row of hb
#define D0   (G2 * NN)           // 24000

// fp32 param-pack offsets (elements)
#define P_EWRAW 0
#define P_SW    96000
#define P_SB    96128
#define P_LNG   96144
#define P_LNB   144144
#define P_C1W   192144
#define P_C1B   192656
#define P_BN1G  192688
#define P_BN1B  192720
#define P_BN1M  192752
#define P_BN1V  192784
#define P_C2W   192816
#define P_C2B   193072
#define P_BN2G  193080
#define P_BN2B  193088
#define P_BN2M  193096
#define P_BN2V  193104
#define P_FB1   193112
#define P_BF1G  193624
#define P_BF1B  194136
#define P_BF1M  194648
#define P_BF1V  195160
#define P_FW2   195672
#define P_FB2   261208
#define P_BF2G  261336
#define P_BF2B  261464
#define P_BF2M  261592
#define P_BF2V  261720
#define P_FOW   261848
#define P_FOB   263128
#define P_TOT   263138

// FC1 K-split: 24000 = 75 chunks x 320; each chunk = 10 MFMA K-steps of 32
#define KCH  320
#define NKC  75

__device__ __forceinline__ float b2f(unsigned short u) {
    union { unsigned int i; float f; } c;
    c.i = ((unsigned int)u) << 16;
    return c.f;
}

__device__ __forceinline__ unsigned short f2b_rne(float x) {
    union { float f; unsigned int u; } c; c.f = x;
    unsigned int r = c.u + 0x7FFFu + ((c.u >> 16) & 1u);
    return (unsigned short)(r >> 16);
}

typedef __attribute__((ext_vector_type(8))) short short8;   // 8 bf16 (4 VGPRs)
typedef __attribute__((ext_vector_type(4))) float f32x4;

// ---------------------------------------------------------------------------
// K_prep: fused dtype sniffs + edge_index convert + histogram + param cvt.
// (R8: x is no longer up-converted — agg reads it natively.)
struct PTab { const void* p[30]; };
__global__ __launch_bounds__(256)
void k_prep(const void* __restrict__ ei_raw, const unsigned int* __restrict__ ewr,
            PTab tab,
            int* __restrict__ ei32, int* __restrict__ cnt, int* __restrict__ flags,
            float* __restrict__ P) {
    __shared__ int sh_is64, sh_bf;
    if (threadIdx.x == 0) {
        const int* pw = (const int*)ei_raw;
        int any = 0;
        #pragma unroll
        for (int i = 1; i < 32; i += 2) any |= pw[i];
        sh_is64 = (any == 0) ? 1 : 0;
        unsigned int w = ewr[0];
        sh_bf = ((w >> 16) == (w & 0xFFFFu)) ? 1 : 0;
        if (blockIdx.x == 0) flags[0] = sh_bf;
    }
    __syncthreads();
    int bf = sh_bf;
    long long gi = (long long)blockIdx.x * blockDim.x + threadIdx.x;
    if (gi < 2 * EE) {
        int i = (int)gi;
        int v = sh_is64 ? (int)((const long long*)ei_raw)[i]
                        : ((const int*)ei_raw)[i];
        ei32[i] = v;
        if (i >= EE) atomicAdd(&cnt[v], 1);   // col half
        return;
    }
    gi -= 2 * EE;
    if (gi >= P_TOT) return;
    int i = (int)gi;
    const int off[31] = {
        P_EWRAW, P_SW, P_SB, P_LNG, P_LNB, P_C1W, P_C1B, P_BN1G, P_BN1B, P_BN1M,
        P_BN1V, P_C2W, P_C2B, P_BN2G, P_BN2B, P_BN2M, P_BN2V, P_FB1, P_BF1G,
        P_BF1B, P_BF1M, P_BF1V, P_FW2, P_FB2, P_BF2G, P_BF2B, P_BF2M, P_BF2V,
        P_FOW, P_FOB, P_TOT };
    int r = 0;
    #pragma unroll
    for (int j = 1; j < 31; ++j) r += (i >= off[j]) ? 1 : 0;
    int e = i - off[r];
    P[i] = bf ? b2f(((const unsigned short*)tab.p[r])[e])
              : ((const float*)tab.p[r])[e];
}

// K2: single-block exclusive scan over N=3000 counts
__global__ void k_scan(const int* __restrict__ cnt, int* __restrict__ off,
                       int* __restrict__ cursor) {
    __shared__ int part[1024];
    int t = threadIdx.x;
    int base = t * 3;
    int c0 = 0, c1 = 0, c2 = 0;
    if (base     < NN) c0 = cnt[base];
    if (base + 1 < NN) c1 = cnt[base + 1];
    if (base + 2 < NN) c2 = cnt[base + 2];
    int s = c0 + c1 + c2;
    part[t] = s;
    __syncthreads();
    for (int d = 1; d < 1024; d <<= 1) {
        int v = (t >= d) ? part[t - d] : 0;
        __syncthreads();
        part[t] += v;
        __syncthreads();
    }
    int excl = part[t] - s;
    if (base < NN)     { off[base]     = excl;           cursor[base]     = excl; }
    if (base + 1 < NN) { off[base + 1] = excl + c0;      cursor[base + 1] = excl + c0; }
    if (base + 2 < NN) { off[base + 2] = excl + c0 + c1; cursor[base + 2] = excl + c0 + c1; }
    if (t == 1023) off[NN] = part[1023];
}

// K3: scatter (row, sigmoid(w)) into CSR order
__global__ void k_scatter(const int* __restrict__ ei, const float* __restrict__ ew,
                          int* __restrict__ cursor,
                          int* __restrict__ rcsr, float* __restrict__ wcsr) {
    int e = blockIdx.x * blockDim.x + threadIdx.x;
    if (e < EE) {
        int p = atomicAdd(&cursor[ei[EE + e]], 1);
        rcsr[p] = ei[e];
        wcsr[p] = 1.f / (1.f + expf(-ew[e]));
    }
}

// K4: per-node scatter-mean + SAGE matmul + ReLU -> hb[b][n][m]
// R8: reads x NATIVELY (bf16 packed uint = 2 elems/lane) — halves gather
// bytes+instructions vs the old fp32 x32 copy; fp32 input keeps old path.
__global__ __launch_bounds__(256)
void k_agg_sage(const void* __restrict__ xraw, const int* __restrict__ flags,
                const int* __restrict__ off,
                const int* __restrict__ rcsr, const float* __restrict__ wcsr,
                const float* __restrict__ sw, const float* __restrict__ sb,
                float* __restrict__ hb) {
    __shared__ float aggL[BC];
    __shared__ float swL[CIN * MID];
    __shared__ float sbL[MID];
    int n = blockIdx.x;
    int t = threadIdx.x;
    if (t < CIN * MID) swL[t] = sw[t];
    if (t < MID)       sbL[t] = sb[t];
    int k0 = off[n], k1 = off[n + 1];
    float a0 = 0.f, a1 = 0.f, b0 = 0.f, b1 = 0.f;
    int k = k0;
    if (flags[0]) {
        const unsigned int* xu = (const unsigned int*)xraw;   // [n][256] uints
        for (; k + 3 < k1; k += 4) {
            int   r0 = rcsr[k],     r1 = rcsr[k + 1];
            int   r2 = rcsr[k + 2], r3 = rcsr[k + 3];
            float w0 = wcsr[k],     w1 = wcsr[k + 1];
            float w2 = wcsr[k + 2], w3 = wcsr[k + 3];
            unsigned int u0 = xu[(size_t)r0 * 256 + t];
            unsigned int u1 = xu[(size_t)r1 * 256 + t];
            unsigned int u2 = xu[(size_t)r2 * 256 + t];
            unsigned int u3 = xu[(size_t)r3 * 256 + t];
            a0 += b2f((unsigned short)(u0 & 0xFFFFu)) * w0;
            a1 += b2f((unsigned short)(u0 >> 16))     * w0;
            b0 += b2f((unsigned short)(u1 & 0xFFFFu)) * w1;
            b1 += b2f((unsigned short)(u1 >> 16))     * w1;
            a0 += b2f((unsigned short)(u2 & 0xFFFFu)) * w2;
            a1 += b2f((unsigned short)(u2 >> 16))     * w2;
            b0 += b2f((unsigned short)(u3 & 0xFFFFu)) * w3;
            b1 += b2f((unsigned short)(u3 >> 16))     * w3;
        }
        for (; k < k1; ++k) {
            int r0 = rcsr[k];
            float w0 = wcsr[k];
            unsigned int u0 = xu[(size_t)r0 * 256 + t];
            a0 += b2f((unsigned short)(u0 & 0xFFFFu)) * w0;
            a1 += b2f((unsigned short)(u0 >> 16))     * w0;
        }
        float inv = 1.f / fmaxf((float)(k1 - k0), 1.f);
        aggL[2 * t]     = (a0 + b0) * inv;
        aggL[2 * t + 1] = (a1 + b1) * inv;
    } else {
        const float* x = (const float*)xraw;
        for (; k + 3 < k1; k += 4) {
            int   r0 = rcsr[k],     r1 = rcsr[k + 1];
            int   r2 = rcsr[k + 2], r3 = rcsr[k + 3];
            float w0 = wcsr[k],     w1 = wcsr[k + 1];
            float w2 = wcsr[k + 2], w3 = wcsr[k + 3];
            const float* xp0 = x + (size_t)r0 * BC;
            const float* xp1 = x + (size_t)r1 * BC;
            const float* xp2 = x + (size_t)r2 * BC;
            const float* xp3 = x + (size_t)r3 * BC;
            a0 += xp0[t]       * w0;  a1 += xp0[t + 256] * w0;
            b0 += xp1[t]       * w1;  b1 += xp1[t + 256] * w1;
            a0 += xp2[t]       * w2;  a1 += xp2[t + 256] * w2;
            b0 += xp3[t]       * w3;  b1 += xp3[t + 256] * w3;
        }
        for (; k < k1; ++k) {
            int r0 = rcsr[k];
            float w0 = wcsr[k];
            const float* xp0 = x + (size_t)r0 * BC;
            a0 += xp0[t] * w0;
            a1 += xp0[t + 256] * w0;
        }
        float inv = 1.f / fmaxf((float)(k1 - k0), 1.f);
        aggL[t]       = (a0 + b0) * inv;
        aggL[t + 256] = (a1 + b1) * inv;
    }
    __syncthreads();
    #pragma unroll
    for (int r4 = 0; r4 < 4; ++r4) {
        int q = t + r4 * 256;
        int b = q >> 4, m = q & 15;
        float v = sbL[m];
        const float* ag = &aggL[b * CIN];
        #pragma unroll
        for (int c = 0; c < CIN; ++c) v += ag[c] * swL[c * MID + m];
        v = fmaxf(v, 0.f);
        hb[(size_t)b * HROW + n * MID + m] = v;
    }
}

// K5: LayerNorm stats per batch element
__global__ __launch_bounds__(256)
void k_ln_stats(const float* __restrict__ hb, float* __restrict__ stats) {
    __shared__ float ssum[256], ssq[256];
    int b = blockIdx.x, t = threadIdx.x;
    const float4* p = (const float4*)(hb + (size_t)b * HROW);
    float s = 0.f, q = 0.f;
    for (int i = t; i < HROW / 4; i += 256) {
        float4 v = p[i];
        s += v.x + v.y + v.z + v.w;
        q += v.x * v.x + v.y * v.y + v.z * v.z + v.w * v.w;
    }
    ssum[t] = s; ssq[t] = q;
    __syncthreads();
    for (int d = 128; d > 0; d >>= 1) {
        if (t < d) { ssum[t] += ssum[t + d]; ssq[t] += ssq[t + d]; }
        __syncthreads();
    }
    if (t == 0) {
        float mu = ssum[0] / (float)HROW;
        float var = ssq[0] / (float)HROW - mu * mu;
        stats[b]      = mu;
        stats[BB + b] = 1.f / sqrtf(var + EPSV);
    }
}

// K6: LN apply + conv1(+relu+bn1) + conv2(+relu+bn2) -> zT as PACKED BF16
// (R8: z enters the bf16 MFMA anyway; hoisting the cast here halves z bytes
// and removes 12M redundant per-fg converts in k_fc1.)
__global__ __launch_bounds__(256)
void k_conv_stack(const float* __restrict__ hb, const float* __restrict__ stats,
                  const float* __restrict__ P, unsigned short* __restrict__ zT) {
    __shared__ float hbt[64 * 65];
    __shared__ float w1s[G1 * MID], w2s[G2 * G1];
    __shared__ float c1s[G1], s1[G1], t1[G1];
    __shared__ float c2s[G2], s2[G2], t2[G2];
    int t = threadIdx.x;
    int n0 = blockIdx.x * 4;
    for (int j = t; j < G1 * MID; j += 256) w1s[j] = P[P_C1W + j];  // 512 > 256
    if (t < G2 * G1)  w2s[t] = P[P_C2W + t];
    if (t < G1) {
        float s = P[P_BN1G + t] / sqrtf(P[P_BN1V + t] + EPSV);
        c1s[t] = P[P_C1B + t]; s1[t] = s; t1[t] = P[P_BN1B + t] - P[P_BN1M + t] * s;
    }
    if (t < G2) {
        float s = P[P_BN2G + t] / sqrtf(P[P_BN2V + t] + EPSV);
        c2s[t] = P[P_C2B + t]; s2[t] = s; t2[t] = P[P_BN2B + t] - P[P_BN2M + t] * s;
    }
    #pragma unroll
    for (int r = 0; r < 4; ++r) {
        int i = r * 256 + t;
        int b = i >> 4, q = i & 15;
        float4 v = *(const float4*)(hb + (size_t)b * HROW + n0 * MID + q * 4);
        int ld = b * 65 + q * 4;
        hbt[ld] = v.x; hbt[ld + 1] = v.y; hbt[ld + 2] = v.z; hbt[ld + 3] = v.w;
    }
    __syncthreads();
    int nl = t >> 6, b = t & 63;
    int n = n0 + nl;
    float mu = stats[b], rs = stats[BB + b];
    float tv[MID];
    #pragma unroll
    for (int m = 0; m < MID; ++m) {
        float g = P[P_LNG + n * MID + m], lb = P[P_LNB + n * MID + m];
        tv[m] = (hbt[b * 65 + nl * MID + m] - mu) * rs * g + lb;
    }
    float v1[G1];
    #pragma unroll
    for (int o = 0; o < G1; ++o) {
        float d = c1s[o];
        #pragma unroll
        for (int m = 0; m < MID; ++m) d += w1s[o * MID + m] * tv[m];
        d = fmaxf(d, 0.f);
        v1[o] = d * s1[o] + t1[o];
    }
    #pragma unroll
    for (int o2 = 0; o2 < G2; ++o2) {
        float d = c2s[o2];
        #pragma unroll
        for (int c = 0; c < G1; ++c) d += w2s[o2 * G1 + c] * v1[c];
        d = fmaxf(d, 0.f);
        zT[((size_t)(o2 * NN + n)) * BB + b] = f2b_rne(d * s2[o2] + t2[o2]);
    }
}

// K7: FC1 partial GEMM via MFMA bf16. C[512f][64b]=W·Z. Block = 4 waves =
// 64f x 64b tile; per 32-k step: A-frag straight from global w1; z (already
// bf16) staged transposed into LDS zs[b][k-pairs] (80-B rows, b128-aligned),
// B-frag = one ds_read_b128. 4 MFMA/wave/step.
__global__ __launch_bounds__(256)
void k_fc1(const unsigned short* __restrict__ zT, const void* __restrict__ w1raw,
           const int* __restrict__ flags, float* __restrict__ out1p) {
    __shared__ unsigned int zs[64 * 20];   // [b][k-pair], row = 20 u32 = 80 B
    int kc = blockIdx.y;
    int t = threadIdx.x;
    int lane = t & 63;
    int wv = t >> 6;
    int n = lane & 15;           // f-row in A, b-col in B/D
    int q = lane >> 4;           // quad: k-group in A/B, row-group in D
    int fbase = blockIdx.x * 64 + wv * 16;
    int bf = flags[0];
    const size_t kcb = (size_t)kc * KCH;
    const float*          w1f = (const float*)w1raw;
    const unsigned short* w1b = (const unsigned short*)w1raw;

    f32x4 acc0 = {0.f, 0.f, 0.f, 0.f};
    f32x4 acc1 = {0.f, 0.f, 0.f, 0.f};
    f32x4 acc2 = {0.f, 0.f, 0.f, 0.f};
    f32x4 acc3 = {0.f, 0.f, 0.f, 0.f};

    int zb = t & 63;             // staging: b
    int kg = t >> 6;             // staging: k-group (0..3)

    for (int ks = 0; ks < KCH / 32; ++ks) {
        size_t k0 = kcb + (size_t)ks * 32;
        // ---- stage z tile (32k x 64b) transposed; z already packed bf16 ----
        const unsigned short* zsrc = zT + (k0 + kg * 8) * BB + zb;
        unsigned short zv[8];
        #pragma unroll
        for (int j = 0; j < 8; ++j) zv[j] = zsrc[j * BB];   // coalesced 2B/lane
        unsigned int pk0 = (unsigned int)zv[0] | ((unsigned int)zv[1] << 16);
        unsigned int pk1 = (unsigned int)zv[2] | ((unsigned int)zv[3] << 16);
        unsigned int pk2 = (unsigned int)zv[4] | ((unsigned int)zv[5] << 16);
        unsigned int pk3 = (unsigned int)zv[6] | ((unsigned int)zv[7] << 16);
        __syncthreads();   // previous step's reads done before overwrite
        *(uint4*)&zs[zb * 20 + kg * 4] = make_uint4(pk0, pk1, pk2, pk3);
        // ---- A fragment from global (no LDS) ----
        short8 av;
        if (bf) {
            av = *(const short8*)(w1b + (size_t)(fbase + n) * D0 + k0 + q * 8);
        } else {
            const float* wr = w1f + (size_t)(fbase + n) * D0 + k0 + q * 8;
            float4 wa = *(const float4*)wr;
            float4 wb = *(const float4*)(wr + 4);
            av[0] = (short)f2b_rne(wa.x); av[1] = (short)f2b_rne(wa.y);
            av[2] = (short)f2b_rne(wa.z); av[3] = (short)f2b_rne(wa.w);
            av[4] = (short)f2b_rne(wb.x); av[5] = (short)f2b_rne(wb.y);
            av[6] = (short)f2b_rne(wb.z); av[7] = (short)f2b_rne(wb.w);
        }
        __syncthreads();   // zs ready
        // ---- 4 B-frags (one per 16-b tile) + MFMA ----
        const char* zbase = (const char*)zs + q * 16;
        short8 bv0 = *(const short8*)(zbase + (0  + n) * 80);
        short8 bv1 = *(const short8*)(zbase + (16 + n) * 80);
        short8 bv2 = *(const short8*)(zbase + (32 + n) * 80);
        short8 bv3 = *(const short8*)(zbase + (48 + n) * 80);
        acc0 = __builtin_amdgcn_mfma_f32_16x16x32_bf16(av, bv0, acc0, 0, 0, 0);
        acc1 = __builtin_amdgcn_mfma_f32_16x16x32_bf16(av, bv1, acc1, 0, 0, 0);
        acc2 = __builtin_amdgcn_mfma_f32_16x16x32_bf16(av, bv2, acc2, 0, 0, 0);
        acc3 = __builtin_amdgcn_mfma_f32_16x16x32_bf16(av, bv3, acc3, 0, 0, 0);
    }
    // ---- store D: lane holds D[fbase + q*4 + r][n], r = 0..3 ----
    float* op = out1p + ((size_t)kc * FC1N + fbase + q * 4) * BB + n;
    #pragma unroll
    for (int r = 0; r < 4; ++r) {
        op[r * BB +  0] = acc0[r];
        op[r * BB + 16] = acc1[r];
        op[r * BB + 32] = acc2[r];
        op[r * BB + 48] = acc3[r];
    }
}

// K8: FC1 reduce partials + bias + bn + relu
__global__ void k_fc1_fin(const float* __restrict__ out1p, const float* __restrict__ P,
                          float* __restrict__ z1) {
    int i = blockIdx.x * blockDim.x + threadIdx.x;
    if (i < BB * FC1N) {
        int f = i >> 6, b = i & 63;
        float acc = 0.f;
        for (int kc = 0; kc < NKC; ++kc)
            acc += out1p[((size_t)kc * FC1N + f) * BB + b];
        acc += P[P_FB1 + f];
        float s = P[P_BF1G + f] / sqrtf(P[P_BF1V + f] + EPSV);
        acc = (acc - P[P_BF1M + f]) * s + P[P_BF1B + f];
        z1[b * FC1N + f] = fmaxf(acc, 0.f);
    }
}

// K9: fused FC2(+bn+relu) + head + softmax; one block per batch element.
__global__ __launch_bounds__(128)
void k_fc2head(const float* __restrict__ z1, const float* __restrict__ P,
               const int* __restrict__ flags, void* __restrict__ outv) {
    __shared__ float zsrc[FC1N];
    __shared__ float z2s[FC2N];
    __shared__ float lg[OUTN];
    __shared__ float red[2];
    int b = blockIdx.x, t = threadIdx.x;
    #pragma unroll
    for (int r = 0; r < 4; ++r) zsrc[t + r * 128] = z1[b * FC1N + t + r * 128];
    __syncthreads();
    {
        int f = t;
        const float4* wr = (const float4*)(P + P_FW2 + (size_t)f * FC1N);
        const float4* zr = (const float4*)zsrc;
        float acc = P[P_FB2 + f];
        for (int k = 0; k < FC1N / 4; ++k) {
            float4 wv = wr[k];
            float4 zv = zr[k];
            acc += wv.x * zv.x + wv.y * zv.y + wv.z * zv.z + wv.w * zv.w;
        }
        float s = P[P_BF2G + f] / sqrtf(P[P_BF2V + f] + EPSV);
        acc = (acc - P[P_BF2M + f]) * s + P[P_BF2B + f];
        z2s[f] = fmaxf(acc, 0.f);
    }
    __syncthreads();
    if (t < OUTN) {
        float acc = P[P_FOB + t];
        const float* wr = P + P_FOW + t * FC2N;
        for (int k = 0; k < FC2N; ++k) acc += wr[k] * z2s[k];
        lg[t] = acc;
    }
    __syncthreads();
    if (t == 0) {
        float mx = lg[0];
        for (int o = 1; o < OUTN; ++o) mx = fmaxf(mx, lg[o]);
        float s = 0.f;
        for (int o = 0; o < OUTN; ++o) s += expf(lg[o] - mx);
        red[0] = mx; red[1] = s;
    }
    __syncthreads();
    if (t < OUTN) {
        float p = expf(lg[t] - red[0]) / red[1];
        if (flags[0]) {
            __hip_bfloat16* o = (__hip_bfloat16*)outv;
            o[b * OUTN + t] = __float2bfloat16(p);
            o[BB * OUTN + b * OUTN + t] = __float2bfloat16(lg[t]);
        } else {
            float* o = (float*)outv;
            o[b * OUTN + t] = p;
            o[BB * OUTN + b * OUTN + t] = lg[t];
        }
    }
}

// ---------------------------------------------------------------------------
extern "C" void kernel_launch(void* const* d_in, const int* in_sizes, int n_in,
                              void* d_out, int out_size, void* d_ws, size_t ws_size,
                              hipStream_t stream) {
    char* ws = (char*)d_ws;
    size_t o = 0;
    auto carve = [&](size_t bytes) { void* p = ws + o; o += (bytes + 255) & ~(size_t)255; return p; };
    int*   flags  = (int*)  carve(16);
    int*   ei32   = (int*)  carve((size_t)2 * EE * sizeof(int));
    int*   cnt    = (int*)  carve(NN * sizeof(int));
    int*   off    = (int*)  carve((NN + 1) * sizeof(int));
    int*   cursor = (int*)  carve(NN * sizeof(int));
    int*   rcsr   = (int*)  carve(EE * sizeof(int));
    float* wcsr   = (float*)carve(EE * sizeof(float));
    float* P      = (float*)carve((size_t)P_TOT * sizeof(float));
    float* hb     = (float*)carve((size_t)BB * HROW * sizeof(float));
    float* stats  = (float*)carve(2 * BB * sizeof(float));
    unsigned short* zT = (unsigned short*)carve((size_t)D0 * BB * sizeof(unsigned short));
    float* out1p  = (float*)carve((size_t)NKC * FC1N * BB * sizeof(float));
    float* z1     = (float*)carve(BB * FC1N * sizeof(float));

    hipMemsetAsync(cnt, 0, NN * sizeof(int), stream);

    PTab tab;
    tab.p[0]  = d_in[2];   tab.p[1]  = d_in[4];   tab.p[2]  = d_in[5];
    tab.p[3]  = d_in[6];   tab.p[4]  = d_in[7];   tab.p[5]  = d_in[8];
    tab.p[6]  = d_in[9];   tab.p[7]  = d_in[10];  tab.p[8]  = d_in[11];
    tab.p[9]  = d_in[12];  tab.p[10] = d_in[13];  tab.p[11] = d_in[14];
    tab.p[12] = d_in[15];  tab.p[13] = d_in[16];  tab.p[14] = d_in[17];
    tab.p[15] = d_in[18];  tab.p[16] = d_in[19];  tab.p[17] = d_in[21];
    tab.p[18] = d_in[22];  tab.p[19] = d_in[23];  tab.p[20] = d_in[24];
    tab.p[21] = d_in[25];  tab.p[22] = d_in[26];  tab.p[23] = d_in[27];
    tab.p[24] = d_in[28];  tab.p[25] = d_in[29];  tab.p[26] = d_in[30];
    tab.p[27] = d_in[31];  tab.p[28] = d_in[32];  tab.p[29] = d_in[33];

    long long prep_tot = 2LL * EE + P_TOT;
    k_prep<<<(int)((prep_tot + 255) / 256), 256, 0, stream>>>(
        d_in[1], (const unsigned int*)d_in[2], tab, ei32, cnt, flags, P);

    k_scan   <<<1, 1024, 0, stream>>>(cnt, off, cursor);
    k_scatter<<<(EE + 255) / 256, 256, 0, stream>>>(ei32, P + P_EWRAW, cursor, rcsr, wcsr);
    k_agg_sage<<<NN, 256, 0, stream>>>(d_in[0], flags, off, rcsr, wcsr,
                                       P + P_SW, P + P_SB, hb);
    k_ln_stats<<<BB, 256, 0, stream>>>(hb, stats);
    k_conv_stack<<<NN / 4, 256, 0, stream>>>(hb, stats, P, zT);
    dim3 g7(FC1N / 64, NKC);
    k_fc1    <<<g7, 256, 0, stream>>>(zT, d_in[20], flags, out1p);
    k_fc1_fin<<<(BB * FC1N + 255) / 256, 256, 0, stream>>>(out1p, P, z1);
    k_fc2head<<<BB, 128, 0, stream>>>(z1, P, flags, (void*)d_out);
}